// Round 8
// baseline (845.458 us; speedup 1.0000x reference)
//
#include <hip/hip_runtime.h>

#define N_NODES 200000
#define N_EDGES 6400000
#define HID 200
#define NREP 4                    // scatter accumulator replicas
#define MT 128                    // nodes per block
#define ASTR 232                  // act row stride (fp16): 464 B, 116 words %32=20 -> 2-way banks (free)
#define APLANE (MT * ASTR)        // 29696 elems = 59392 B
#define WSTR 232
#define WROWS 224                 // g_wph padded rows (layout kept from R7)
#define WELEMS (WROWS * WSTR)     // 51968 elems per layer in g_wph
#define SROWS 208                 // rows actually staged (13 tiles of 16)
#define SELEMS (SROWS * WSTR)     // 48256 elems = 96512 B staged per layer
#define SCHUNK (SELEMS / 8)       // 6032 16-B chunks
#define NCH 6                     // ceil(6032/1024) chunks per thread

// LDS map: act [0, 59392) ; wlds [59392, 155904) ; h0s aliased at [59392, 59904)
#define LDS_W 59392
#define LDS_TOTAL 155904

typedef float f32x4 __attribute__((ext_vector_type(4)));
typedef _Float16 f16x8 __attribute__((ext_vector_type(8)));
typedef unsigned short u16;
typedef unsigned int u32;

__device__ __align__(16) float g_agg[NREP * N_NODES];
__device__ __align__(16) float g_wf[6 * HID * HID];      // fp32 (VALU fallback)
__device__ __align__(16) _Float16 g_wph[6 * WELEMS];     // fp16 W^T padded [l][n][k]
__device__ int g_isbf;

__device__ __forceinline__ float bf2f(u16 u) {
  union { u32 i; float f; } v; v.i = ((u32)u) << 16; return v.f;
}
__device__ __forceinline__ u16 f2bf(float f) {  // RNE
  u32 i = __float_as_uint(f);
  return (u16)((i + 0x7FFFu + ((i >> 16) & 1u)) >> 16);
}
__device__ __forceinline__ float ldf(const void* p, int i, int isbf) {
  return isbf ? bf2f(((const u16*)p)[i]) : ((const float*)p)[i];
}

// ---- rank-2 MFMA layout self-test (fp16), reference folded at compile time ----
constexpr int tf1(int m) { return (m & 3) + 1; }
constexpr int tf2(int m) { return ((m >> 2) & 3) + 2; }
constexpr int tg1(int k) { return (k & 7) + 1; }
constexpr int tg2(int k) { return ((k >> 3) & 3) + 1; }
constexpr int tu1(int k) { return ((k * 3) & 7) + 1; }
constexpr int tu2(int k) { return ((k >> 2) & 3) + 2; }
constexpr int tw1(int n) { return ((n * 5) & 7) + 1; }
constexpr int tw2(int n) { return ((n >> 2) & 3) + 1; }
constexpr int calcS(int i, int j) {
  int s = 0;
  for (int k = 0; k < 32; ++k)
    s += (i ? tg2(k) : tg1(k)) * (j ? tu2(k) : tu1(k));
  return s;
}
__device__ __forceinline__ float refD(int m, int n) {
  constexpr int S11 = calcS(0, 0), S12 = calcS(0, 1), S21 = calcS(1, 0), S22 = calcS(1, 1);
  return (float)(tf1(m) * tw1(n) * S11 + tf1(m) * tw2(n) * S12 +
                 tf2(m) * tw1(n) * S21 + tf2(m) * tw2(n) * S22);
}
__device__ int mfma_selftest(int l15, int q) {
  f16x8 av, bv;
#pragma unroll
  for (int j = 0; j < 8; ++j) {
    int k = q * 8 + j;
    av[j] = (_Float16)(float)(tf1(l15) * tg1(k) + tf2(l15) * tg2(k));
    bv[j] = (_Float16)(float)(tu1(k) * tw1(l15) + tu2(k) * tw2(l15));
  }
  f32x4 d = __builtin_amdgcn_mfma_f32_16x16x32_f16(av, bv, (f32x4){0.f, 0.f, 0.f, 0.f}, 0, 0, 0);
  bool ok0 = true, ok1 = true;
#pragma unroll
  for (int r = 0; r < 4; ++r) {
    ok0 = ok0 && (d[r] == refD(q * 4 + r, l15));
    ok1 = ok1 && (d[r] == refD(l15, q * 4 + r));
  }
  return __all(ok0) ? 0 : (__all(ok1) ? 1 : 2);
}

// ---- K0: dtype sniff ----
__global__ void sniff_kernel(const u32* __restrict__ xw) {
  int i = threadIdx.x;  // 64 threads
  u32 e = (xw[i] >> 7) & 0xFFu;
  unsigned long long b = __ballot(e >= 110u && e <= 135u);
  if (i == 0) g_isbf = (__popcll(b) >= 48) ? 1 : 0;
}

// ---- K1: zero replicas + both weight forms ----
__global__ void prep_kernel(const void* __restrict__ w_hid) {
  int t = blockIdx.x * blockDim.x + threadIdx.x;
  int isbf = g_isbf;
  if (t < NREP * N_NODES) g_agg[t] = 0.f;
  if (t < 6 * HID * HID) g_wf[t] = ldf(w_hid, t, isbf);
  if (t < 6 * WELEMS) {
    int l = t / WELEMS;
    int r = t - l * WELEMS;
    int n = r / WSTR;
    int k = r - n * WSTR;
    float v = 0.f;
    if (n < HID && k < HID) v = ldf(w_hid, (l * HID + k) * HID + n, isbf);
    g_wph[t] = (_Float16)v;
  }
}

// ---- K2: edge scatter-add (frozen from R6/R7) ----
__global__ void scatter_kernel(const int* __restrict__ ei, const void* __restrict__ x) {
  int t = blockIdx.x * blockDim.x + threadIdx.x;
  int e = t * 4;
  int isbf = g_isbf;
  float* agg = g_agg + (size_t)(blockIdx.x & (NREP - 1)) * N_NODES;
  bool is64 = ((ei[1] | ei[3] | ei[5] | ei[7]) == 0);
  int s0, s1, s2, s3, d0, d1, d2, d3;
  if (is64) {
    int4 a = *(const int4*)(ei + 2 * e);
    int4 b = *(const int4*)(ei + 2 * e + 4);
    int4 c = *(const int4*)(ei + 2 * N_EDGES + 2 * e);
    int4 d = *(const int4*)(ei + 2 * N_EDGES + 2 * e + 4);
    s0 = a.x; s1 = a.z; s2 = b.x; s3 = b.z;
    d0 = c.x; d1 = c.z; d2 = d.x; d3 = d.z;
  } else {
    int4 s4 = *(const int4*)(ei + e);
    int4 d4 = *(const int4*)(ei + N_EDGES + e);
    s0 = s4.x; s1 = s4.y; s2 = s4.z; s3 = s4.w;
    d0 = d4.x; d1 = d4.y; d2 = d4.z; d3 = d4.w;
  }
  atomicAdd(&agg[d0], ldf(x, s0, isbf));
  atomicAdd(&agg[d1], ldf(x, s1, isbf));
  atomicAdd(&agg[d2], ldf(x, s2, isbf));
  atomicAdd(&agg[d3], ldf(x, s3, isbf));
}

// ---- K3: fused MLP; weights VGPR-prefetched one layer ahead ----
__global__ __launch_bounds__(1024) void mlp_kernel(
    const void* __restrict__ x,
    const void* __restrict__ w_rel, const void* __restrict__ b_rel, const void* __restrict__ w_root,
    const void* __restrict__ w_in, const void* __restrict__ b_in,
    const void* __restrict__ b_hid, const void* __restrict__ w_out, const void* __restrict__ b_out,
    void* __restrict__ out) {
  extern __shared__ char smem[];
  _Float16* act = (_Float16*)smem;
  _Float16* wlds = (_Float16*)(smem + LDS_W);
  float* h0s = (float*)(smem + LDS_W);  // aliased; dead before first wlds write

  const int tid = threadIdx.x;
  const int nb = blockIdx.x * MT;
  const int isbf = g_isbf;
  const int lane = tid & 63;
  const int wv = tid >> 6;
  const int l15 = lane & 15;
  const int q = lane >> 4;

  const int mode = mfma_selftest(l15, q);

  // GraphConv h0 (replica-summed), tail-guarded
  if (tid < MT) {
    int node = nb + tid;
    float v = 0.f;
    if (node < N_NODES) {
      float a = g_agg[node] + g_agg[N_NODES + node] +
                g_agg[2 * N_NODES + node] + g_agg[3 * N_NODES + node];
      v = a * ldf(w_rel, 0, isbf) + ldf(b_rel, 0, isbf) +
          ldf(x, node, isbf) * ldf(w_root, 0, isbf);
    }
    h0s[tid] = v;
  }

  if (mode < 2) {
    // Prefetch layer 0 weight chunks into VGPRs (overlaps input layer)
    f16x8 pre[NCH];
#pragma unroll
    for (int i = 0; i < NCH; ++i) {
      int c = tid + i * 1024;
      if (c < SCHUNK) pre[i] = *(const f16x8*)(g_wph + c * 8);
    }

    __syncthreads();  // h0s ready
    // Input layer: act[m][j] = relu(h0[m]*w_in[j]+b_in[j]); pad cols zeroed
    for (int idx = tid; idx < APLANE; idx += 1024) {
      int m = idx / ASTR, j = idx - m * ASTR;
      float v = 0.f;
      if (j < HID) {
        v = h0s[m] * ldf(w_in, j, isbf) + ldf(b_in, j, isbf);
        v = fmaxf(v, 0.f);
      }
      act[idx] = (_Float16)v;
    }

    const int band = wv >> 2;                    // 4 bands x 32 rows (Mt=2)
    const int g = wv & 3;                        // col groups: tiles 4/3/3/3 (13 total)
    const int ct0 = (g == 0) ? 0 : 4 + (g - 1) * 3;
    const int cnt = (g == 0) ? 4 : 3;

    for (int l = 0; l < 6; ++l) {
      __syncthreads();  // act stable; wlds reads of layer l-1 all complete

      // commit prefetched chunks to LDS, then issue next layer's loads
#pragma unroll
      for (int i = 0; i < NCH; ++i) {
        int c = tid + i * 1024;
        if (c < SCHUNK) *(f16x8*)(wlds + c * 8) = pre[i];
      }
      const _Float16* wgn = g_wph + (l < 5 ? l + 1 : 5) * WELEMS;
#pragma unroll
      for (int i = 0; i < NCH; ++i) {
        int c = tid + i * 1024;
        if (c < SCHUNK) pre[i] = *(const f16x8*)(wgn + c * 8);
      }
      __syncthreads();  // wlds populated

      f32x4 acc[2][4];
#pragma unroll
      for (int h = 0; h < 2; ++h)
#pragma unroll
        for (int n = 0; n < 4; ++n) acc[h][n] = (f32x4){0.f, 0.f, 0.f, 0.f};

      const _Float16* ap = act + (band * 32 + l15) * ASTR + q * 8;
      const _Float16* bp = wlds + (ct0 * 16 + l15) * WSTR + q * 8;
#pragma unroll
      for (int ks = 0; ks < 7; ++ks) {
        f16x8 a0 = *(const f16x8*)(ap + ks * 32);
        f16x8 a1 = *(const f16x8*)(ap + 16 * ASTR + ks * 32);
#pragma unroll
        for (int n = 0; n < 4; ++n) {
          if (n < cnt) {
            f16x8 b = *(const f16x8*)(bp + n * 16 * WSTR + ks * 32);
            acc[0][n] = __builtin_amdgcn_mfma_f32_16x16x32_f16(a0, b, acc[0][n], 0, 0, 0);
            acc[1][n] = __builtin_amdgcn_mfma_f32_16x16x32_f16(a1, b, acc[1][n], 0, 0, 0);
          }
        }
      }
      __syncthreads();  // all act/wlds reads done before in-place writes

      // epilogue: bias + relu, in-place fp16 (per-wave disjoint cols)
#pragma unroll
      for (int n = 0; n < 4; ++n) {
        if (n < cnt) {
          int ctile = (ct0 + n) * 16;
#pragma unroll
          for (int h = 0; h < 2; ++h) {
#pragma unroll
            for (int r = 0; r < 4; ++r) {
              int rr = (mode == 0) ? (q * 4 + r) : l15;
              int cc = (mode == 0) ? l15 : (q * 4 + r);
              int row = band * 32 + h * 16 + rr, col = ctile + cc;
              float v = acc[h][n][r] + ((col < HID) ? ldf(b_hid, l * HID + col, isbf) : 0.f);
              act[row * ASTR + col] = (_Float16)fmaxf(v, 0.f);
            }
          }
        }
      }
    }

    __syncthreads();
    // Output layer: 8 threads per row, 25 cols each
    {
      int m = tid >> 3, c = tid & 7;
      const _Float16* ar = act + m * ASTR;
      float s = 0.f;
#pragma unroll
      for (int j = c * 25; j < c * 25 + 25; ++j)
        s += (float)ar[j] * ldf(w_out, j, isbf);
      s += __shfl_down(s, 4);
      s += __shfl_down(s, 2);
      s += __shfl_down(s, 1);
      int node = nb + m;
      if (c == 0 && node < N_NODES) {
        float logit = s + ldf(b_out, 0, isbf);
        float o = 1.f / (1.f + __expf(-logit));
        if (isbf) ((u16*)out)[node] = f2bf(o);
        else ((float*)out)[node] = o;
      }
    }
  } else {
    // ---- VALU fallback (defensive; 2 passes of 64 nodes) ----
    __syncthreads();
    float(*fA)[201] = (float(*)[201])smem;
    float(*fB)[201] = (float(*)[201])(smem + LDS_W + 512);
    for (int p = 0; p < 2; ++p) {
      __syncthreads();
      for (int i = tid; i < 64 * HID; i += 1024) {
        int mm = i / HID, ff = i - mm * HID;
        float v = h0s[p * 64 + mm] * ldf(w_in, ff, isbf) + ldf(b_in, ff, isbf);
        fA[mm][ff] = v > 0.f ? v : 0.f;
      }
      __syncthreads();
      const int m = tid >> 4, c = tid & 15;
      float(*ain)[201] = fA;
      float(*aout)[201] = fB;
      for (int l = 0; l < 6; ++l) {
        float acc[13];
#pragma unroll
        for (int jj = 0; jj < 13; ++jj) {
          int j = c * 13 + jj;
          acc[jj] = (j < HID) ? ldf(b_hid, l * HID + j, isbf) : 0.f;
        }
        const float* wl = g_wf + l * HID * HID;
        for (int k = 0; k < HID; ++k) {
          float a = ain[m][k];
          const float* wr = wl + k * HID;
#pragma unroll
          for (int jj = 0; jj < 13; ++jj) {
            int j = c * 13 + jj;
            if (j < HID) acc[jj] = fmaf(a, wr[j], acc[jj]);
          }
        }
        __syncthreads();
#pragma unroll
        for (int jj = 0; jj < 13; ++jj) {
          int j = c * 13 + jj;
          if (j < HID) aout[m][j] = fmaxf(acc[jj], 0.f);
        }
        float(*tsw)[201] = ain; ain = aout; aout = tsw;
        __syncthreads();
      }
      float s = 0.f;
      for (int j = c * 13; j < c * 13 + 13 && j < HID; ++j)
        s += ain[m][j] * ldf(w_out, j, isbf);
      s += __shfl_down(s, 8);
      s += __shfl_down(s, 4);
      s += __shfl_down(s, 2);
      s += __shfl_down(s, 1);
      int node = nb + p * 64 + m;
      if (c == 0 && node < N_NODES) {
        float logit = s + ldf(b_out, 0, isbf);
        float o = 1.f / (1.f + __expf(-logit));
        if (isbf) ((u16*)out)[node] = f2bf(o);
        else ((float*)out)[node] = o;
      }
    }
  }
}

extern "C" void kernel_launch(void* const* d_in, const int* in_sizes, int n_in,
                              void* d_out, int out_size, void* d_ws, size_t ws_size,
                              hipStream_t stream) {
  const void* x      = d_in[0];
  const int* ei      = (const int*)d_in[1];
  const void* w_rel  = d_in[2];
  const void* b_rel  = d_in[3];
  const void* w_root = d_in[4];
  const void* w_in   = d_in[5];
  const void* b_in   = d_in[6];
  const void* w_hid  = d_in[7];
  const void* b_hid  = d_in[8];
  const void* w_out  = d_in[9];
  const void* b_out  = d_in[10];
  (void)d_ws; (void)ws_size; (void)in_sizes; (void)n_in; (void)out_size;

  sniff_kernel<<<1, 64, 0, stream>>>((const u32*)x);
  prep_kernel<<<(NREP * N_NODES + 255) / 256, 256, 0, stream>>>(w_hid);
  scatter_kernel<<<N_EDGES / 4 / 256, 256, 0, stream>>>(ei, x);
  mlp_kernel<<<(N_NODES + MT - 1) / MT, 1024, LDS_TOTAL, stream>>>(
      x, w_rel, b_rel, w_root, w_in, b_in, b_hid, w_out, b_out, d_out);
}

// Round 9
// 843.586 us; speedup vs baseline: 1.0022x; 1.0022x over previous
//
#include <hip/hip_runtime.h>

#define N_NODES 200000
#define N_EDGES 6400000
#define HID 200
#define NREP 4                    // scatter accumulator replicas
#define MT 128                    // nodes per block
#define ASTR 232                  // act row stride (fp16): 464 B, 116 words %32=20 -> 2-way banks (free)
#define APLANE (MT * ASTR)        // 29696 elems = 59392 B
#define WSTR 232
#define WROWS 224                 // g_wph padded rows
#define WELEMS (WROWS * WSTR)     // 51968 elems per layer in g_wph
#define SROWS 208                 // rows actually staged (13 tiles of 16)
#define SELEMS (SROWS * WSTR)     // 48256 elems = 96512 B staged per layer
#define SCHUNK (SELEMS / 8)       // 6032 16-B chunks
#define NCH 6                     // ceil(6032/1024) chunks per thread

// LDS map: act [0, 59392) ; wlds [59392, 155904) ; h0s aliased at [59392, 59904)
#define LDS_W 59392
#define LDS_TOTAL 155904

typedef float f32x4 __attribute__((ext_vector_type(4)));
typedef _Float16 f16x8 __attribute__((ext_vector_type(8)));
typedef unsigned short u16;
typedef unsigned int u32;

__device__ __align__(16) float g_agg[NREP * N_NODES];
__device__ __align__(16) float g_wf[6 * HID * HID];      // fp32 (VALU fallback)
__device__ __align__(16) _Float16 g_wph[6 * WELEMS];     // fp16 W^T padded [l][n][k]
__device__ int g_isbf;

__device__ __forceinline__ float bf2f(u16 u) {
  union { u32 i; float f; } v; v.i = ((u32)u) << 16; return v.f;
}
__device__ __forceinline__ u16 f2bf(float f) {  // RNE
  u32 i = __float_as_uint(f);
  return (u16)((i + 0x7FFFu + ((i >> 16) & 1u)) >> 16);
}
__device__ __forceinline__ float ldf(const void* p, int i, int isbf) {
  return isbf ? bf2f(((const u16*)p)[i]) : ((const float*)p)[i];
}

// ---- rank-2 MFMA layout self-test (fp16), reference folded at compile time ----
constexpr int tf1(int m) { return (m & 3) + 1; }
constexpr int tf2(int m) { return ((m >> 2) & 3) + 2; }
constexpr int tg1(int k) { return (k & 7) + 1; }
constexpr int tg2(int k) { return ((k >> 3) & 3) + 1; }
constexpr int tu1(int k) { return ((k * 3) & 7) + 1; }
constexpr int tu2(int k) { return ((k >> 2) & 3) + 2; }
constexpr int tw1(int n) { return ((n * 5) & 7) + 1; }
constexpr int tw2(int n) { return ((n >> 2) & 3) + 1; }
constexpr int calcS(int i, int j) {
  int s = 0;
  for (int k = 0; k < 32; ++k)
    s += (i ? tg2(k) : tg1(k)) * (j ? tu2(k) : tu1(k));
  return s;
}
__device__ __forceinline__ float refD(int m, int n) {
  constexpr int S11 = calcS(0, 0), S12 = calcS(0, 1), S21 = calcS(1, 0), S22 = calcS(1, 1);
  return (float)(tf1(m) * tw1(n) * S11 + tf1(m) * tw2(n) * S12 +
                 tf2(m) * tw1(n) * S21 + tf2(m) * tw2(n) * S22);
}
__device__ int mfma_selftest(int l15, int q) {
  f16x8 av, bv;
#pragma unroll
  for (int j = 0; j < 8; ++j) {
    int k = q * 8 + j;
    av[j] = (_Float16)(float)(tf1(l15) * tg1(k) + tf2(l15) * tg2(k));
    bv[j] = (_Float16)(float)(tu1(k) * tw1(l15) + tu2(k) * tw2(l15));
  }
  f32x4 d = __builtin_amdgcn_mfma_f32_16x16x32_f16(av, bv, (f32x4){0.f, 0.f, 0.f, 0.f}, 0, 0, 0);
  bool ok0 = true, ok1 = true;
#pragma unroll
  for (int r = 0; r < 4; ++r) {
    ok0 = ok0 && (d[r] == refD(q * 4 + r, l15));
    ok1 = ok1 && (d[r] == refD(l15, q * 4 + r));
  }
  return __all(ok0) ? 0 : (__all(ok1) ? 1 : 2);
}

// ---- K0: dtype sniff ----
__global__ void sniff_kernel(const u32* __restrict__ xw) {
  int i = threadIdx.x;  // 64 threads
  u32 e = (xw[i] >> 7) & 0xFFu;
  unsigned long long b = __ballot(e >= 110u && e <= 135u);
  if (i == 0) g_isbf = (__popcll(b) >= 48) ? 1 : 0;
}

// ---- K1: zero replicas + both weight forms ----
__global__ void prep_kernel(const void* __restrict__ w_hid) {
  int t = blockIdx.x * blockDim.x + threadIdx.x;
  int isbf = g_isbf;
  if (t < NREP * N_NODES) g_agg[t] = 0.f;
  if (t < 6 * HID * HID) g_wf[t] = ldf(w_hid, t, isbf);
  if (t < 6 * WELEMS) {
    int l = t / WELEMS;
    int r = t - l * WELEMS;
    int n = r / WSTR;
    int k = r - n * WSTR;
    float v = 0.f;
    if (n < HID && k < HID) v = ldf(w_hid, (l * HID + k) * HID + n, isbf);
    g_wph[t] = (_Float16)v;
  }
}

// ---- K2: edge scatter-add (frozen from R6/R7) ----
__global__ void scatter_kernel(const int* __restrict__ ei, const void* __restrict__ x) {
  int t = blockIdx.x * blockDim.x + threadIdx.x;
  int e = t * 4;
  int isbf = g_isbf;
  float* agg = g_agg + (size_t)(blockIdx.x & (NREP - 1)) * N_NODES;
  bool is64 = ((ei[1] | ei[3] | ei[5] | ei[7]) == 0);
  int s0, s1, s2, s3, d0, d1, d2, d3;
  if (is64) {
    int4 a = *(const int4*)(ei + 2 * e);
    int4 b = *(const int4*)(ei + 2 * e + 4);
    int4 c = *(const int4*)(ei + 2 * N_EDGES + 2 * e);
    int4 d = *(const int4*)(ei + 2 * N_EDGES + 2 * e + 4);
    s0 = a.x; s1 = a.z; s2 = b.x; s3 = b.z;
    d0 = c.x; d1 = c.z; d2 = d.x; d3 = d.z;
  } else {
    int4 s4 = *(const int4*)(ei + e);
    int4 d4 = *(const int4*)(ei + N_EDGES + e);
    s0 = s4.x; s1 = s4.y; s2 = s4.z; s3 = s4.w;
    d0 = d4.x; d1 = d4.y; d2 = d4.z; d3 = d4.w;
  }
  atomicAdd(&agg[d0], ldf(x, s0, isbf));
  atomicAdd(&agg[d1], ldf(x, s1, isbf));
  atomicAdd(&agg[d2], ldf(x, s2, isbf));
  atomicAdd(&agg[d3], ldf(x, s3, isbf));
}

// ---- K3: fused MLP; weights VGPR-prefetched one layer ahead ----
// __launch_bounds__(1024, 4): 16 waves/block at 1 block/CU = 4 waves/EU.
// This grants ~128 VGPRs/wave — R8's plain (1024) capped at 64 and SPILLED
// the pre[] prefetch to scratch (WRITE_SIZE 122 MB, +5 GB fetch, +77 us).
__global__ __launch_bounds__(1024, 4) void mlp_kernel(
    const void* __restrict__ x,
    const void* __restrict__ w_rel, const void* __restrict__ b_rel, const void* __restrict__ w_root,
    const void* __restrict__ w_in, const void* __restrict__ b_in,
    const void* __restrict__ b_hid, const void* __restrict__ w_out, const void* __restrict__ b_out,
    void* __restrict__ out) {
  extern __shared__ char smem[];
  _Float16* act = (_Float16*)smem;
  _Float16* wlds = (_Float16*)(smem + LDS_W);
  float* h0s = (float*)(smem + LDS_W);  // aliased; dead before first wlds write

  const int tid = threadIdx.x;
  const int nb = blockIdx.x * MT;
  const int isbf = g_isbf;
  const int lane = tid & 63;
  const int wv = tid >> 6;
  const int l15 = lane & 15;
  const int q = lane >> 4;

  const int mode = mfma_selftest(l15, q);

  // GraphConv h0 (replica-summed), tail-guarded
  if (tid < MT) {
    int node = nb + tid;
    float v = 0.f;
    if (node < N_NODES) {
      float a = g_agg[node] + g_agg[N_NODES + node] +
                g_agg[2 * N_NODES + node] + g_agg[3 * N_NODES + node];
      v = a * ldf(w_rel, 0, isbf) + ldf(b_rel, 0, isbf) +
          ldf(x, node, isbf) * ldf(w_root, 0, isbf);
    }
    h0s[tid] = v;
  }

  if (mode < 2) {
    // Prefetch layer 0 weight chunks into VGPRs (overlaps input layer)
    f16x8 pre[NCH];
#pragma unroll
    for (int i = 0; i < NCH; ++i) {
      int c = tid + i * 1024;
      if (c < SCHUNK) pre[i] = *(const f16x8*)(g_wph + c * 8);
    }

    __syncthreads();  // h0s ready
    // Input layer: act[m][j] = relu(h0[m]*w_in[j]+b_in[j]); pad cols zeroed
    for (int idx = tid; idx < APLANE; idx += 1024) {
      int m = idx / ASTR, j = idx - m * ASTR;
      float v = 0.f;
      if (j < HID) {
        v = h0s[m] * ldf(w_in, j, isbf) + ldf(b_in, j, isbf);
        v = fmaxf(v, 0.f);
      }
      act[idx] = (_Float16)v;
    }

    const int band = wv >> 2;                    // 4 bands x 32 rows (Mt=2)
    const int g = wv & 3;                        // col groups: tiles 4/3/3/3 (13 total)
    const int ct0 = (g == 0) ? 0 : 4 + (g - 1) * 3;
    const int cnt = (g == 0) ? 4 : 3;

    for (int l = 0; l < 6; ++l) {
      __syncthreads();  // act stable; wlds reads of layer l-1 all complete

      // commit prefetched chunks to LDS, then issue next layer's loads
#pragma unroll
      for (int i = 0; i < NCH; ++i) {
        int c = tid + i * 1024;
        if (c < SCHUNK) *(f16x8*)(wlds + c * 8) = pre[i];
      }
      const _Float16* wgn = g_wph + (l < 5 ? l + 1 : 5) * WELEMS;
#pragma unroll
      for (int i = 0; i < NCH; ++i) {
        int c = tid + i * 1024;
        if (c < SCHUNK) pre[i] = *(const f16x8*)(wgn + c * 8);
      }
      __syncthreads();  // wlds populated

      f32x4 acc[2][4];
#pragma unroll
      for (int h = 0; h < 2; ++h)
#pragma unroll
        for (int n = 0; n < 4; ++n) acc[h][n] = (f32x4){0.f, 0.f, 0.f, 0.f};

      const _Float16* ap = act + (band * 32 + l15) * ASTR + q * 8;
      const _Float16* bp = wlds + (ct0 * 16 + l15) * WSTR + q * 8;
#pragma unroll
      for (int ks = 0; ks < 7; ++ks) {
        f16x8 a0 = *(const f16x8*)(ap + ks * 32);
        f16x8 a1 = *(const f16x8*)(ap + 16 * ASTR + ks * 32);
#pragma unroll
        for (int n = 0; n < 4; ++n) {
          if (n < cnt) {
            f16x8 b = *(const f16x8*)(bp + n * 16 * WSTR + ks * 32);
            acc[0][n] = __builtin_amdgcn_mfma_f32_16x16x32_f16(a0, b, acc[0][n], 0, 0, 0);
            acc[1][n] = __builtin_amdgcn_mfma_f32_16x16x32_f16(a1, b, acc[1][n], 0, 0, 0);
          }
        }
      }
      __syncthreads();  // all act/wlds reads done before in-place writes

      // epilogue: bias + relu, in-place fp16 (per-wave disjoint cols)
#pragma unroll
      for (int n = 0; n < 4; ++n) {
        if (n < cnt) {
          int ctile = (ct0 + n) * 16;
#pragma unroll
          for (int h = 0; h < 2; ++h) {
#pragma unroll
            for (int r = 0; r < 4; ++r) {
              int rr = (mode == 0) ? (q * 4 + r) : l15;
              int cc = (mode == 0) ? l15 : (q * 4 + r);
              int row = band * 32 + h * 16 + rr, col = ctile + cc;
              float v = acc[h][n][r] + ((col < HID) ? ldf(b_hid, l * HID + col, isbf) : 0.f);
              act[row * ASTR + col] = (_Float16)fmaxf(v, 0.f);
            }
          }
        }
      }
    }

    __syncthreads();
    // Output layer: 8 threads per row, 25 cols each
    {
      int m = tid >> 3, c = tid & 7;
      const _Float16* ar = act + m * ASTR;
      float s = 0.f;
#pragma unroll
      for (int j = c * 25; j < c * 25 + 25; ++j)
        s += (float)ar[j] * ldf(w_out, j, isbf);
      s += __shfl_down(s, 4);
      s += __shfl_down(s, 2);
      s += __shfl_down(s, 1);
      int node = nb + m;
      if (c == 0 && node < N_NODES) {
        float logit = s + ldf(b_out, 0, isbf);
        float o = 1.f / (1.f + __expf(-logit));
        if (isbf) ((u16*)out)[node] = f2bf(o);
        else ((float*)out)[node] = o;
      }
    }
  } else {
    // ---- VALU fallback (defensive; 2 passes of 64 nodes) ----
    __syncthreads();
    float(*fA)[201] = (float(*)[201])smem;
    float(*fB)[201] = (float(*)[201])(smem + LDS_W + 512);
    for (int p = 0; p < 2; ++p) {
      __syncthreads();
      for (int i = tid; i < 64 * HID; i += 1024) {
        int mm = i / HID, ff = i - mm * HID;
        float v = h0s[p * 64 + mm] * ldf(w_in, ff, isbf) + ldf(b_in, ff, isbf);
        fA[mm][ff] = v > 0.f ? v : 0.f;
      }
      __syncthreads();
      const int m = tid >> 4, c = tid & 15;
      float(*ain)[201] = fA;
      float(*aout)[201] = fB;
      for (int l = 0; l < 6; ++l) {
        float acc[13];
#pragma unroll
        for (int jj = 0; jj < 13; ++jj) {
          int j = c * 13 + jj;
          acc[jj] = (j < HID) ? ldf(b_hid, l * HID + j, isbf) : 0.f;
        }
        const float* wl = g_wf + l * HID * HID;
        for (int k = 0; k < HID; ++k) {
          float a = ain[m][k];
          const float* wr = wl + k * HID;
#pragma unroll
          for (int jj = 0; jj < 13; ++jj) {
            int j = c * 13 + jj;
            if (j < HID) acc[jj] = fmaf(a, wr[j], acc[jj]);
          }
        }
        __syncthreads();
#pragma unroll
        for (int jj = 0; jj < 13; ++jj) {
          int j = c * 13 + jj;
          if (j < HID) aout[m][j] = fmaxf(acc[jj], 0.f);
        }
        float(*tsw)[201] = ain; ain = aout; aout = tsw;
        __syncthreads();
      }
      float s = 0.f;
      for (int j = c * 13; j < c * 13 + 13 && j < HID; ++j)
        s += ain[m][j] * ldf(w_out, j, isbf);
      s += __shfl_down(s, 8);
      s += __shfl_down(s, 4);
      s += __shfl_down(s, 2);
      s += __shfl_down(s, 1);
      int node = nb + p * 64 + m;
      if (c == 0 && node < N_NODES) {
        float logit = s + ldf(b_out, 0, isbf);
        float o = 1.f / (1.f + __expf(-logit));
        if (isbf) ((u16*)out)[node] = f2bf(o);
        else ((float*)out)[node] = o;
      }
    }
  }
}

extern "C" void kernel_launch(void* const* d_in, const int* in_sizes, int n_in,
                              void* d_out, int out_size, void* d_ws, size_t ws_size,
                              hipStream_t stream) {
  const void* x      = d_in[0];
  const int* ei      = (const int*)d_in[1];
  const void* w_rel  = d_in[2];
  const void* b_rel  = d_in[3];
  const void* w_root = d_in[4];
  const void* w_in   = d_in[5];
  const void* b_in   = d_in[6];
  const void* w_hid  = d_in[7];
  const void* b_hid  = d_in[8];
  const void* w_out  = d_in[9];
  const void* b_out  = d_in[10];
  (void)d_ws; (void)ws_size; (void)in_sizes; (void)n_in; (void)out_size;

  sniff_kernel<<<1, 64, 0, stream>>>((const u32*)x);
  prep_kernel<<<(NREP * N_NODES + 255) / 256, 256, 0, stream>>>(w_hid);
  scatter_kernel<<<N_EDGES / 4 / 256, 256, 0, stream>>>(ei, x);
  mlp_kernel<<<(N_NODES + MT - 1) / MT, 1024, LDS_TOTAL, stream>>>(
      x, w_rel, b_rel, w_root, w_in, b_in, b_hid, w_out, b_out, d_out);
}